// Round 5
// baseline (138.354 us; speedup 1.0000x reference)
//
#include <hip/hip_runtime.h>
#include <math.h>

#define BS 8
#define NF 32
#define NLOC 65536
#define DELTA_VAR 0.5f
#define DELTA_DIST 1.5f
#define GAMMA 1e-4f
#define G 128      // blocks per batch
#define CHUNK 512  // NLOC / G

// ws float layout
#define WS_COUNTS 0     // [BS][2] = 16
#define WS_MEANS  16    // [BS][NF][2] = 512
#define WS_VARSUM 528   // [BS][2], each slot on its own 128B line (*32) = 512
#define WS_CTR    1040  // done-counter (u32), padded to 1072
#define WS_PART   1072  // [BS][G][68]: 64 (f x {sx,s0}) + cnt0 (+3 pad)
#define WS_LABELS (1072 + BS * G * 68)  // u8 [BS][NLOC] after partials

// ======== Kernel A: partial sums + labels (validated R3 structure) ========
// one-hot, labels in {0,1}: t1 = 1-t0, rows 2,3 == 0. Per feature accumulate
// sx = sum(x), s0 = sum(x*t0). Wave fg owns features fg*8..fg*8+7.
__global__ __launch_bounds__(256, 4) void k_sums(const float* __restrict__ inp,
                                                 const float* __restrict__ tgt,
                                                 float* __restrict__ ws,
                                                 unsigned char* __restrict__ labels) {
  float* part = ws + WS_PART;
  const int b = blockIdx.y;
  const int gx = blockIdx.x;
  const int tid = threadIdx.x;
  const int lane = tid & 63;
  const int fg = tid >> 6;
  const int n0 = gx * CHUNK;
  const float* inp_b = inp + (size_t)b * NF * NLOC + (size_t)fg * 8 * NLOC;
  const float* t0_b = tgt + (size_t)b * 4 * NLOC;  // row 0

  float r[16];  // r[i*2]=sx_i, r[i*2+1]=s0_i
#pragma unroll
  for (int k = 0; k < 16; ++k) r[k] = 0.f;
  float cnt0 = 0.f;

#pragma unroll
  for (int it = 0; it < CHUNK / 256; ++it) {
    const int n = n0 + it * 256 + lane * 4;
    float4 t0 = *reinterpret_cast<const float4*>(t0_b + n);
    float4 x[8];
#pragma unroll
    for (int i = 0; i < 8; ++i)
      x[i] = *reinterpret_cast<const float4*>(inp_b + i * NLOC + n);
    if (fg == 0) {
      cnt0 += t0.x + t0.y + t0.z + t0.w;
      uchar4 l4;
      l4.x = t0.x > 0.5f ? 0 : 1;
      l4.y = t0.y > 0.5f ? 0 : 1;
      l4.z = t0.z > 0.5f ? 0 : 1;
      l4.w = t0.w > 0.5f ? 0 : 1;
      *reinterpret_cast<uchar4*>(labels + (size_t)b * NLOC + n) = l4;
    }
#pragma unroll
    for (int i = 0; i < 8; ++i) {
      r[i * 2 + 0] += x[i].x + x[i].y + x[i].z + x[i].w;
      r[i * 2 + 1] += x[i].x * t0.x + x[i].y * t0.y + x[i].z * t0.z + x[i].w * t0.w;
    }
  }

  // transposed butterfly: 16 values over 64 lanes -> lane 4k holds out[k]
#define BSTEP(m, half)                                      \
  {                                                         \
    _Pragma("unroll") for (int j = 0; j < half; ++j) {      \
      float aa = __shfl_xor(r[j], m, 64);                   \
      float bb = __shfl_xor(r[j + half], m, 64);            \
      r[j] = (lane & m) ? (r[j + half] + bb) : (r[j] + aa); \
    }                                                       \
  }
  BSTEP(32, 8)
  BSTEP(16, 4)
  BSTEP(8, 2)
  BSTEP(4, 1)
#undef BSTEP
  r[0] += __shfl_xor(r[0], 2, 64);
  r[0] += __shfl_xor(r[0], 1, 64);

  __shared__ float pp[68];
  if ((lane & 3) == 0) pp[fg * 16 + (lane >> 2)] = r[0];

  if (fg == 0) {
    cnt0 += __shfl_xor(cnt0, 32, 64);
    cnt0 += __shfl_xor(cnt0, 16, 64);
    cnt0 += __shfl_xor(cnt0, 8, 64);
    cnt0 += __shfl_xor(cnt0, 4, 64);
    cnt0 += __shfl_xor(cnt0, 2, 64);
    cnt0 += __shfl_xor(cnt0, 1, 64);
    if (lane == 0) pp[64] = cnt0;
  }
  __syncthreads();
  if (tid < 65) part[((size_t)(b * G + gx)) * 68 + tid] = pp[tid];
  // zero varsum + done-counter for kernel B (kernel boundary = visibility)
  if (gx == 0 && tid < 2) ws[WS_VARSUM + (b * 2 + tid) * 32] = 0.f;
  if (gx == 0 && b == 0 && tid == 0)
    *reinterpret_cast<unsigned int*>(ws + WS_CTR) = 0u;
}

// ======== Kernel B: redundant means-reduce + var pass + last-block epilogue
__global__ __launch_bounds__(256, 4) void k_var(const float* __restrict__ inp,
                                                const unsigned char* __restrict__ labels,
                                                const int* __restrict__ ncl,
                                                float* __restrict__ ws,
                                                float* __restrict__ out) {
  const int b = blockIdx.y;
  const int gx = blockIdx.x;
  const int tid = threadIdx.x;
  const int lane = tid & 63;
  const int fg = tid >> 6;

  __shared__ float sbuf[4][64];
  __shared__ float tbuf[64];
  __shared__ float cbuf[G];
  __shared__ float cnt_s[2];
  __shared__ float2 m_lds[NF];
  __shared__ float vred[4][2];
  __shared__ int last_flag;

  // ---- Phase 1: reduce own batch's partials -> means in LDS ----
  {
    const float* pb = ws + WS_PART + (size_t)b * G * 68;
    const int q = tid >> 6, rem = tid & 63;
    float s = 0.f;
    for (int g2 = q * 32; g2 < q * 32 + 32; ++g2) s += pb[(size_t)g2 * 68 + rem];
    sbuf[q][rem] = s;
    if (tid < G) cbuf[tid] = pb[(size_t)tid * 68 + 64];
    __syncthreads();
    if (tid < 64) {
      tbuf[tid] = sbuf[0][tid] + sbuf[1][tid] + sbuf[2][tid] + sbuf[3][tid];
      float c = cbuf[tid] + cbuf[tid + 64];
      c += __shfl_xor(c, 32, 64);
      c += __shfl_xor(c, 16, 64);
      c += __shfl_xor(c, 8, 64);
      c += __shfl_xor(c, 4, 64);
      c += __shfl_xor(c, 2, 64);
      c += __shfl_xor(c, 1, 64);
      if (tid == 0) {
        cnt_s[0] = c;
        cnt_s[1] = (float)NLOC - c;
      }
    }
    __syncthreads();
    if (tid < 32) {
      const int f = tid;  // t*2 == (t>>3)*16 + (t&7)*2 identically
      float sx = tbuf[f * 2], s0 = tbuf[f * 2 + 1];
      float c0 = cnt_s[0], c1 = cnt_s[1];
      float m0 = c0 > 0.f ? s0 / c0 : 0.f;
      float m1 = c1 > 0.f ? (sx - s0) / c1 : 0.f;
      m_lds[f] = make_float2(m0, m1);
      if (gx == 0) {
        ws[WS_MEANS + (b * NF + f) * 2 + 0] = m0;
        ws[WS_MEANS + (b * NF + f) * 2 + 1] = m1;
        if (f < 2) ws[WS_COUNTS + b * 2 + f] = cnt_s[f];
      }
    }
    __syncthreads();
  }

  // ---- Phase 2: var pass over own chunk ----
  {
    const float* inp_b = inp + (size_t)b * NF * NLOC;
    const int n = gx * CHUNK + tid * 2;
    const uchar2 lab = *reinterpret_cast<const uchar2*>(labels + (size_t)b * NLOC + n);
    float ax = 0.f, ay = 0.f;
#pragma unroll
    for (int f = 0; f < NF; ++f) {
      float2 x = *reinterpret_cast<const float2*>(inp_b + f * NLOC + n);
      float2 m = m_lds[f];
      float mx = lab.x ? m.y : m.x;
      float my = lab.y ? m.y : m.x;
      float dx = x.x - mx, dy = x.y - my;
      ax += dx * dx;
      ay += dy * dy;
    }
    float vx = fmaxf(sqrtf(ax) - DELTA_VAR, 0.f);
    float vy = fmaxf(sqrtf(ay) - DELTA_VAR, 0.f);
    vx *= vx;
    vy *= vy;
    float vacc0 = (lab.x ? 0.f : vx) + (lab.y ? 0.f : vy);
    float vacc1 = (lab.x ? vx : 0.f) + (lab.y ? vy : 0.f);

    float aa = __shfl_xor(vacc0, 32, 64);
    float bb = __shfl_xor(vacc1, 32, 64);
    float u = (lane & 32) ? (vacc1 + bb) : (vacc0 + aa);
    u += __shfl_xor(u, 16, 64);
    u += __shfl_xor(u, 8, 64);
    u += __shfl_xor(u, 4, 64);
    u += __shfl_xor(u, 2, 64);
    u += __shfl_xor(u, 1, 64);
    if ((lane & 31) == 0) vred[fg][lane >> 5] = u;
    __syncthreads();
    if (tid < 2) {
      float s = vred[0][tid] + vred[1][tid] + vred[2][tid] + vred[3][tid];
      atomicAdd(&ws[WS_VARSUM + (b * 2 + tid) * 32], s);
    }
  }

  // ---- Phase 3: last arriving block computes the epilogue ----
  __threadfence();
  __syncthreads();
  if (tid == 0) {
    unsigned int* ctr = reinterpret_cast<unsigned int*>(ws + WS_CTR);
    unsigned int old =
        __hip_atomic_fetch_add(ctr, 1u, __ATOMIC_ACQ_REL, __HIP_MEMORY_SCOPE_AGENT);
    last_flag = (old == (unsigned int)(G * BS - 1)) ? 1 : 0;
  }
  __syncthreads();
  if (!last_flag) return;

  __shared__ float eme[BS * NF * 2];  // 512
  __shared__ float ecnt[BS * 2];
  __shared__ float evs[BS * 2];
  for (int k = tid; k < BS * NF * 2; k += 256)
    eme[k] = __hip_atomic_load(ws + WS_MEANS + k, __ATOMIC_RELAXED,
                               __HIP_MEMORY_SCOPE_AGENT);
  if (tid < BS * 2) {
    ecnt[tid] = __hip_atomic_load(ws + WS_COUNTS + tid, __ATOMIC_RELAXED,
                                  __HIP_MEMORY_SCOPE_AGENT);
    evs[tid] = __hip_atomic_load(ws + WS_VARSUM + tid * 32, __ATOMIC_RELAXED,
                                 __HIP_MEMORY_SCOPE_AGENT);
  }
  __syncthreads();
  if (tid < 64) {
    float total = 0.f;
    if (tid < BS) {
      const int bb2 = tid;
      const float nc = (float)ncl[bb2];
      float c0 = ecnt[bb2 * 2 + 0], c1 = ecnt[bb2 * 2 + 1];
      float v0 = evs[bb2 * 2 + 0], v1 = evs[bb2 * 2 + 1];
      float sv = (c0 > 0.f ? v0 / c0 : 0.f) + (c1 > 0.f ? v1 / c1 : 0.f);
      float l_var = sv / nc;
      float d2 = 0.f, n0s = 0.f, n1s = 0.f;
      for (int f = 0; f < NF; ++f) {
        float m0 = eme[(bb2 * NF + f) * 2 + 0];
        float m1 = eme[(bb2 * NF + f) * 2 + 1];
        float df = m0 - m1;
        d2 += df * df;
        n0s += m0 * m0;
        n1s += m1 * m1;
      }
      float dn = d2 > 0.f ? sqrtf(d2) : 0.f;
      float h = fmaxf(2.f * DELTA_DIST - dn, 0.f);
      float l_dist = 2.f * h * h / (2.f * nc * (nc - 1.f));
      float r0 = n0s > 0.f ? sqrtf(n0s) : 0.f;
      float r1 = n1s > 0.f ? sqrtf(n1s) : 0.f;
      float l_reg = 0.5f * (r0 + r1);
      total = l_var + l_dist + GAMMA * l_reg;
    }
#pragma unroll
    for (int m = 1; m < 8; m <<= 1) total += __shfl_xor(total, m, 64);
    if (tid == 0) out[0] = total / (float)BS;
  }
}

extern "C" void kernel_launch(void* const* d_in, const int* in_sizes, int n_in,
                              void* d_out, int out_size, void* d_ws, size_t ws_size,
                              hipStream_t stream) {
  const float* inp = (const float*)d_in[0];
  const float* tgt = (const float*)d_in[1];
  const int* ncl = (const int*)d_in[2];
  float* out = (float*)d_out;
  float* ws = (float*)d_ws;
  unsigned char* labels = (unsigned char*)(ws + WS_LABELS);

  k_sums<<<dim3(G, BS), 256, 0, stream>>>(inp, tgt, ws, labels);
  k_var<<<dim3(G, BS), 256, 0, stream>>>(inp, labels, ncl, ws, out);
}

// Round 6
// 34.058 us; speedup vs baseline: 4.0623x; 4.0623x over previous
//
#include <hip/hip_runtime.h>
#include <math.h>

#define BS 8
#define NF 32
#define NLOC 65536
#define DELTA_VAR 0.5f
#define DELTA_DIST 1.5f
#define GAMMA 1e-4f
#define G 128       // k_sums blocks per batch
#define CHUNK 512   // NLOC / G
#define G2 64       // k_var blocks per batch
#define CHUNK2 1024 // NLOC / G2

// ws float layout
#define WS_COUNTS 0     // [BS][2] = 16
#define WS_MEANS  16    // [BS][NF][2] = 512
#define WS_VARSUM 528   // [BS][2], each slot on its own 128B line (*32) = 512
#define WS_PART   1040  // [BS][G][68]: 64 (f x {sx,s0}) + cnt0 (+3 pad)
#define WS_LABELS (1040 + BS * G * 68)  // u8 [BS][NLOC] after partials

// ======== Kernel A: partial sums + labels (validated R3/R5 math) ========
__global__ __launch_bounds__(256, 4) void k_sums(const float* __restrict__ inp,
                                                 const float* __restrict__ tgt,
                                                 float* __restrict__ ws,
                                                 unsigned char* __restrict__ labels) {
  float* part = ws + WS_PART;
  const int b = blockIdx.y;
  const int gx = blockIdx.x;
  const int tid = threadIdx.x;
  const int lane = tid & 63;
  const int fg = tid >> 6;
  const int n0 = gx * CHUNK;
  const float* inp_b = inp + (size_t)b * NF * NLOC + (size_t)fg * 8 * NLOC;
  const float* t0_b = tgt + (size_t)b * 4 * NLOC;  // one-hot row 0

  float r[16];  // r[i*2]=sx_i, r[i*2+1]=s0_i
#pragma unroll
  for (int k = 0; k < 16; ++k) r[k] = 0.f;
  float cnt0 = 0.f;

#pragma unroll
  for (int it = 0; it < CHUNK / 256; ++it) {
    const int n = n0 + it * 256 + lane * 4;
    float4 t0 = *reinterpret_cast<const float4*>(t0_b + n);
    float4 x[8];
#pragma unroll
    for (int i = 0; i < 8; ++i)
      x[i] = *reinterpret_cast<const float4*>(inp_b + i * NLOC + n);
    if (fg == 0) {
      cnt0 += t0.x + t0.y + t0.z + t0.w;
      uchar4 l4;
      l4.x = t0.x > 0.5f ? 0 : 1;
      l4.y = t0.y > 0.5f ? 0 : 1;
      l4.z = t0.z > 0.5f ? 0 : 1;
      l4.w = t0.w > 0.5f ? 0 : 1;
      *reinterpret_cast<uchar4*>(labels + (size_t)b * NLOC + n) = l4;
    }
#pragma unroll
    for (int i = 0; i < 8; ++i) {
      r[i * 2 + 0] += x[i].x + x[i].y + x[i].z + x[i].w;
      r[i * 2 + 1] += x[i].x * t0.x + x[i].y * t0.y + x[i].z * t0.z + x[i].w * t0.w;
    }
  }

#define BSTEP(m, half)                                      \
  {                                                         \
    _Pragma("unroll") for (int j = 0; j < half; ++j) {      \
      float aa = __shfl_xor(r[j], m, 64);                   \
      float bb = __shfl_xor(r[j + half], m, 64);            \
      r[j] = (lane & m) ? (r[j + half] + bb) : (r[j] + aa); \
    }                                                       \
  }
  BSTEP(32, 8)
  BSTEP(16, 4)
  BSTEP(8, 2)
  BSTEP(4, 1)
#undef BSTEP
  r[0] += __shfl_xor(r[0], 2, 64);
  r[0] += __shfl_xor(r[0], 1, 64);

  __shared__ float pp[68];
  if ((lane & 3) == 0) pp[fg * 16 + (lane >> 2)] = r[0];

  if (fg == 0) {
    cnt0 += __shfl_xor(cnt0, 32, 64);
    cnt0 += __shfl_xor(cnt0, 16, 64);
    cnt0 += __shfl_xor(cnt0, 8, 64);
    cnt0 += __shfl_xor(cnt0, 4, 64);
    cnt0 += __shfl_xor(cnt0, 2, 64);
    cnt0 += __shfl_xor(cnt0, 1, 64);
    if (lane == 0) pp[64] = cnt0;
  }
  __syncthreads();
  if (tid < 65) part[((size_t)(b * G + gx)) * 68 + tid] = pp[tid];
  if (gx == 0 && tid < 2) ws[WS_VARSUM + (b * 2 + tid) * 32] = 0.f;
}

// ======== Kernel B: redundant per-batch means-reduce + float4 var pass ====
__global__ __launch_bounds__(256, 4) void k_var(const float* __restrict__ inp,
                                                const unsigned char* __restrict__ labels,
                                                float* __restrict__ ws) {
  const int b = blockIdx.y;
  const int gx = blockIdx.x;
  const int tid = threadIdx.x;
  const int lane = tid & 63;
  const int fg = tid >> 6;

  __shared__ float sbuf[4][64];
  __shared__ float tbuf[64];
  __shared__ float cbuf[G];
  __shared__ float cnt_s[2];
  __shared__ float2 m_lds[NF];
  __shared__ float vred[4][2];

  // ---- Phase 1: reduce own batch's partials -> means in LDS (plain loads)
  {
    const float* pb = ws + WS_PART + (size_t)b * G * 68;
    const int q = tid >> 6, rem = tid & 63;
    float s = 0.f;
    for (int g2 = q * 32; g2 < q * 32 + 32; ++g2) s += pb[(size_t)g2 * 68 + rem];
    sbuf[q][rem] = s;
    if (tid < G) cbuf[tid] = pb[(size_t)tid * 68 + 64];
    __syncthreads();
    if (tid < 64) {
      tbuf[tid] = sbuf[0][tid] + sbuf[1][tid] + sbuf[2][tid] + sbuf[3][tid];
      float c = cbuf[tid] + cbuf[tid + 64];
      c += __shfl_xor(c, 32, 64);
      c += __shfl_xor(c, 16, 64);
      c += __shfl_xor(c, 8, 64);
      c += __shfl_xor(c, 4, 64);
      c += __shfl_xor(c, 2, 64);
      c += __shfl_xor(c, 1, 64);
      if (tid == 0) {
        cnt_s[0] = c;
        cnt_s[1] = (float)NLOC - c;
      }
    }
    __syncthreads();
    if (tid < 32) {
      const int f = tid;
      float sx = tbuf[f * 2], s0 = tbuf[f * 2 + 1];
      float c0 = cnt_s[0], c1 = cnt_s[1];
      float m0 = c0 > 0.f ? s0 / c0 : 0.f;
      float m1 = c1 > 0.f ? (sx - s0) / c1 : 0.f;
      m_lds[f] = make_float2(m0, m1);
      if (gx == 0) {
        ws[WS_MEANS + (b * NF + f) * 2 + 0] = m0;
        ws[WS_MEANS + (b * NF + f) * 2 + 1] = m1;
        if (f < 2) ws[WS_COUNTS + b * 2 + f] = cnt_s[f];
      }
    }
    __syncthreads();
  }

  // ---- Phase 2: var pass, float4 / thread ----
  {
    const float* inp_b = inp + (size_t)b * NF * NLOC;
    const int n = gx * CHUNK2 + tid * 4;
    const uchar4 lab = *reinterpret_cast<const uchar4*>(labels + (size_t)b * NLOC + n);
    float a0 = 0.f, a1 = 0.f, a2 = 0.f, a3 = 0.f;
#pragma unroll
    for (int f = 0; f < NF; ++f) {
      float4 x = *reinterpret_cast<const float4*>(inp_b + f * NLOC + n);
      float2 m = m_lds[f];
      float m0 = lab.x ? m.y : m.x;
      float m1 = lab.y ? m.y : m.x;
      float m2 = lab.z ? m.y : m.x;
      float m3 = lab.w ? m.y : m.x;
      float d0 = x.x - m0, d1 = x.y - m1, d2 = x.z - m2, d3 = x.w - m3;
      a0 += d0 * d0;
      a1 += d1 * d1;
      a2 += d2 * d2;
      a3 += d3 * d3;
    }
    float v0 = fmaxf(sqrtf(a0) - DELTA_VAR, 0.f);
    float v1 = fmaxf(sqrtf(a1) - DELTA_VAR, 0.f);
    float v2 = fmaxf(sqrtf(a2) - DELTA_VAR, 0.f);
    float v3 = fmaxf(sqrtf(a3) - DELTA_VAR, 0.f);
    v0 *= v0; v1 *= v1; v2 *= v2; v3 *= v3;
    float vacc0 = (lab.x ? 0.f : v0) + (lab.y ? 0.f : v1) +
                  (lab.z ? 0.f : v2) + (lab.w ? 0.f : v3);
    float vacc1 = (lab.x ? v0 : 0.f) + (lab.y ? v1 : 0.f) +
                  (lab.z ? v2 : 0.f) + (lab.w ? v3 : 0.f);

    float aa = __shfl_xor(vacc0, 32, 64);
    float bb = __shfl_xor(vacc1, 32, 64);
    float u = (lane & 32) ? (vacc1 + bb) : (vacc0 + aa);
    u += __shfl_xor(u, 16, 64);
    u += __shfl_xor(u, 8, 64);
    u += __shfl_xor(u, 4, 64);
    u += __shfl_xor(u, 2, 64);
    u += __shfl_xor(u, 1, 64);
    if ((lane & 31) == 0) vred[fg][lane >> 5] = u;
    __syncthreads();
    if (tid < 2) {
      float s = vred[0][tid] + vred[1][tid] + vred[2][tid] + vred[3][tid];
      atomicAdd(&ws[WS_VARSUM + (b * 2 + tid) * 32], s);
    }
  }
}

// ======== Kernel C: epilogue ========
__global__ void k_final(const float* __restrict__ ws,
                        const int* __restrict__ ncl,
                        float* __restrict__ out) {
  const int tid = threadIdx.x;
  float total = 0.f;
  if (tid < BS) {
    const int b = tid;
    const float nc = (float)ncl[b];
    float c0 = ws[WS_COUNTS + b * 2 + 0], c1 = ws[WS_COUNTS + b * 2 + 1];
    float v0 = ws[WS_VARSUM + (b * 2 + 0) * 32], v1 = ws[WS_VARSUM + (b * 2 + 1) * 32];
    float sv = (c0 > 0.f ? v0 / c0 : 0.f) + (c1 > 0.f ? v1 / c1 : 0.f);
    float l_var = sv / nc;
    float d2 = 0.f, n0s = 0.f, n1s = 0.f;
    for (int f = 0; f < NF; ++f) {
      float m0 = ws[WS_MEANS + (b * NF + f) * 2 + 0];
      float m1 = ws[WS_MEANS + (b * NF + f) * 2 + 1];
      float df = m0 - m1;
      d2 += df * df;
      n0s += m0 * m0;
      n1s += m1 * m1;
    }
    float dn = d2 > 0.f ? sqrtf(d2) : 0.f;
    float h = fmaxf(2.f * DELTA_DIST - dn, 0.f);
    float l_dist = 2.f * h * h / (2.f * nc * (nc - 1.f));
    float r0 = n0s > 0.f ? sqrtf(n0s) : 0.f;
    float r1 = n1s > 0.f ? sqrtf(n1s) : 0.f;
    float l_reg = 0.5f * (r0 + r1);
    total = l_var + l_dist + GAMMA * l_reg;
  }
#pragma unroll
  for (int m = 1; m < 8; m <<= 1) total += __shfl_xor(total, m, 64);
  if (tid == 0) out[0] = total / (float)BS;
}

extern "C" void kernel_launch(void* const* d_in, const int* in_sizes, int n_in,
                              void* d_out, int out_size, void* d_ws, size_t ws_size,
                              hipStream_t stream) {
  const float* inp = (const float*)d_in[0];
  const float* tgt = (const float*)d_in[1];
  const int* ncl = (const int*)d_in[2];
  float* out = (float*)d_out;
  float* ws = (float*)d_ws;
  unsigned char* labels = (unsigned char*)(ws + WS_LABELS);

  k_sums<<<dim3(G, BS), 256, 0, stream>>>(inp, tgt, ws, labels);
  k_var<<<dim3(G2, BS), 256, 0, stream>>>(inp, labels, ws);
  k_final<<<1, 64, 0, stream>>>(ws, ncl, out);
}